// Round 4
// baseline (48.159 us; speedup 1.0000x reference)
//
#include <hip/hip_runtime.h>

// TreeLoss: 2-level hierarchical softmax loss.
// z(b)       = 1 + sum_p e^{x_p} * (1 + sum_{c in p} e^{x_c})   (parents p=56..63)
// marginal(b)= e^{x_g} * e^{x_parent(g)},  parent(g) = 56 + g/7
// loss(b)    = log(z / marginal); output = mean over batch.
//
// R4: fused single kernel.
//  - 512 threads/block, 256 rows/block staged exp'd into LDS (stride 65:
//    bank = (row + col)%32 -> exactly 2 lanes/bank on both phases = free).
//    Same 66.5KB LDS as R3 but 2x waves -> 16 waves/CU (50% occupancy).
//  - Compute split: thread t does parents 0..3 of row t&255, thread t+256
//    does parents 4..7 -> all 512 threads active, half the serial work.
//  - Last-block-finishes final reduction (release partial stores + acq_rel
//    counter, agent scope -> correct across non-coherent per-XCD L2s).
//    Deterministic: every partial is complete before the finalizer runs and
//    the summation order is a fixed ascending loop.

#define RPB     256
#define ROW_PAD 65
#define THREADS 512

__global__ void __launch_bounds__(THREADS) tree_loss_fused(
    const float* __restrict__ pred,    // [rows, 64]
    const int*   __restrict__ gt,      // [rows] 0..55
    float*       __restrict__ partial, // [gridDim.x]
    int*         __restrict__ counter, // zeroed by host memset each call
    float*       __restrict__ out,
    int rows, float inv)
{
    __shared__ float lds[RPB * ROW_PAD];   // 66560 B
    __shared__ float zhalf[THREADS];       // 2 KB
    __shared__ float wsum[THREADS / 64];
    __shared__ int   lastFlag;

    const int t = threadIdx.x;
    const int rowBase = blockIdx.x * RPB;
    const bool full = (rowBase + RPB <= rows);

    // ---- Stage: coalesced float4, exp in-flight. 4096 float4 / 512 thr = 8.
    const float4* p4 = (const float4*)pred + (size_t)rowBase * 16;
    #pragma unroll
    for (int i = 0; i < 8; ++i) {
        int f   = i * THREADS + t;      // 0..4095
        int row = f >> 4;               // 0..255
        int col = (f & 15) << 2;        // 0..60
        if (full || rowBase + row < rows) {
            float4 v = p4[f];
            float* dst = &lds[row * ROW_PAD + col];
            dst[0] = __expf(v.x); dst[1] = __expf(v.y);
            dst[2] = __expf(v.z); dst[3] = __expf(v.w);
        }
    }
    __syncthreads();

    // ---- Half-row z per thread: hi=0 -> parents 0..3, hi=1 -> parents 4..7.
    {
        const int r  = t & (RPB - 1);
        const int hi = t >> 8;
        float zh = 0.0f;
        if (full || rowBase + r < rows) {
            const float* e  = &lds[r * ROW_PAD];
            const float* ec = e + hi * 28;       // 28 children
            const float* ep = e + 56 + hi * 4;   // 4 parents
            #pragma unroll
            for (int p = 0; p < 4; ++p) {
                float s = 1.0f;
                #pragma unroll
                for (int c = 0; c < 7; ++c) s += ec[p * 7 + c];
                zh += ep[p] * s;
            }
        }
        zhalf[t] = zh;
    }
    __syncthreads();

    // ---- Finish one row per thread (t<256); upper half contributes 0.
    float loss = 0.0f;
    if (t < RPB) {
        const int rowg = rowBase + t;
        if (rowg < rows) {
            float z = 1.0f + zhalf[t] + zhalf[t + RPB];
            const float* e = &lds[t * ROW_PAD];
            int g = gt[rowg];                    // coalesced
            float m = e[g] * e[56 + g / 7];
            loss = __logf(z / m);
        }
    }
    #pragma unroll
    for (int off = 32; off; off >>= 1) loss += __shfl_xor(loss, off);
    if ((t & 63) == 0) wsum[t >> 6] = loss;
    __syncthreads();

    // ---- Publish block partial; last block finalizes.
    if (t == 0) {
        float b = 0.0f;
        #pragma unroll
        for (int w = 0; w < THREADS / 64; ++w) b += wsum[w];
        __hip_atomic_store(&partial[blockIdx.x], b,
                           __ATOMIC_RELEASE, __HIP_MEMORY_SCOPE_AGENT);
        int old = __hip_atomic_fetch_add(counter, 1,
                                         __ATOMIC_ACQ_REL, __HIP_MEMORY_SCOPE_AGENT);
        lastFlag = (old == (int)gridDim.x - 1);
    }
    __syncthreads();

    if (lastFlag) {
        float s = 0.0f;
        for (int i = t; i < (int)gridDim.x; i += THREADS)
            s += __hip_atomic_load(&partial[i],
                                   __ATOMIC_ACQUIRE, __HIP_MEMORY_SCOPE_AGENT);
        #pragma unroll
        for (int off = 32; off; off >>= 1) s += __shfl_xor(s, off);
        if ((t & 63) == 0) wsum[t >> 6] = s;
        __syncthreads();
        if (t == 0) {
            float b = 0.0f;
            #pragma unroll
            for (int w = 0; w < THREADS / 64; ++w) b += wsum[w];
            out[0] = b * inv;
        }
    }
}

extern "C" void kernel_launch(void* const* d_in, const int* in_sizes, int n_in,
                              void* d_out, int out_size, void* d_ws, size_t ws_size,
                              hipStream_t stream) {
    const float* pred = (const float*)d_in[0];   // [B,64] fp32
    const int*   gt   = (const int*)d_in[1];     // [B] int32
    float* out = (float*)d_out;
    const int rows = in_sizes[1];                // BATCH = 262144

    const int blocks = (rows + RPB - 1) / RPB;   // 1024
    float* partial = (float*)d_ws;
    int*   counter = (int*)((char*)d_ws + ((size_t)blocks * sizeof(float) + 255 & ~(size_t)255));

    // Re-zero the arrival counter every call (graph-captured, async).
    hipMemsetAsync(counter, 0, sizeof(int), stream);

    tree_loss_fused<<<blocks, THREADS, 0, stream>>>(
        pred, gt, partial, counter, out, rows, 1.0f / (float)rows);
}

// Round 5
// 21.274 us; speedup vs baseline: 2.2638x; 2.2638x over previous
//
#include <hip/hip_runtime.h>

// TreeLoss: 2-level hierarchical softmax loss.
// z(b)       = 1 + sum_p e^{x_p} * (1 + sum_{c in p} e^{x_c})   (parents p=56..63)
// marginal(b)= e^{x_g} * e^{x_parent(g)},  parent(g) = 56 + g/7
// loss(b)    = log(z / marginal); output = mean over batch.
//
// R5: two kernels again (R4's fused last-block-finishes regressed 22.7->48us:
// 1024 agent-scope ACQ_REL atomics on one line serialized block retirement).
// vs R3: halve the LDS tile (128 rows, 33.3KB) -> 4 blocks/CU = 16 waves/CU
// (was 2 blocks / 8 waves), and use all 256 threads in the z-phase by
// splitting each row across 2 threads (parents 0-3 / 4-7).

#define RPB     128                 // rows per block
#define ROW_PAD 65                  // (row+col)%32 bank pattern: 2 lanes/bank = free
#define THREADS 256

__global__ void __launch_bounds__(THREADS) tree_loss_partial(
    const float* __restrict__ pred,   // [rows, 64]
    const int*   __restrict__ gt,     // [rows] 0..55
    float*       __restrict__ partial,// [gridDim.x]
    int rows)
{
    __shared__ float lds[RPB * ROW_PAD];   // 33280 B -> 4 blocks/CU
    __shared__ float zhalf[THREADS];       // 1 KB
    __shared__ float wsum[THREADS / 64];

    const int t = threadIdx.x;
    const int rowBase = blockIdx.x * RPB;
    const bool full = (rowBase + RPB <= rows);

    // ---- Stage: coalesced float4, exp in-flight. 128*16=2048 float4 / 256 thr = 8.
    const float4* p4 = (const float4*)pred + (size_t)rowBase * 16;
    #pragma unroll
    for (int i = 0; i < 8; ++i) {
        int f   = i * THREADS + t;      // 0..2047
        int row = f >> 4;               // 0..127
        int col = (f & 15) << 2;        // 0..60
        if (full || rowBase + row < rows) {
            float4 v = p4[f];
            float* dst = &lds[row * ROW_PAD + col];
            dst[0] = __expf(v.x); dst[1] = __expf(v.y);
            dst[2] = __expf(v.z); dst[3] = __expf(v.w);
        }
    }
    __syncthreads();

    // ---- Half-row z per thread: hi=0 -> parents 0..3, hi=1 -> parents 4..7.
    {
        const int r  = t & (RPB - 1);
        const int hi = t >> 7;
        float zh = 0.0f;
        if (full || rowBase + r < rows) {
            const float* e  = &lds[r * ROW_PAD];
            const float* ec = e + hi * 28;       // 28 children
            const float* ep = e + 56 + hi * 4;   // 4 parents
            #pragma unroll
            for (int p = 0; p < 4; ++p) {
                float s = 1.0f;
                #pragma unroll
                for (int c = 0; c < 7; ++c) s += ec[p * 7 + c];
                zh += ep[p] * s;
            }
        }
        zhalf[t] = zh;
    }
    __syncthreads();

    // ---- Finish one row per thread (t < 128).
    float loss = 0.0f;
    if (t < RPB) {
        const int rowg = rowBase + t;
        if (rowg < rows) {
            float z = 1.0f + zhalf[t] + zhalf[t + RPB];
            const float* e = &lds[t * ROW_PAD];
            int g = gt[rowg];                    // coalesced
            float m = e[g] * e[56 + g / 7];
            loss = __logf(z / m);
        }
    }

    // ---- Block reduction ----
    #pragma unroll
    for (int off = 32; off; off >>= 1) loss += __shfl_xor(loss, off);
    if ((t & 63) == 0) wsum[t >> 6] = loss;
    __syncthreads();
    if (t == 0) {
        float b = 0.0f;
        #pragma unroll
        for (int w = 0; w < THREADS / 64; ++w) b += wsum[w];
        partial[blockIdx.x] = b;
    }
}

__global__ void __launch_bounds__(256) tree_loss_final(
    const float* __restrict__ partial, int n,
    float* __restrict__ out, float inv)
{
    float s = 0.0f;
    for (int i = threadIdx.x; i < n; i += 256) s += partial[i];
    #pragma unroll
    for (int off = 32; off; off >>= 1) s += __shfl_xor(s, off);
    __shared__ float w[4];
    const int lane = threadIdx.x & 63;
    const int wv   = threadIdx.x >> 6;
    if (lane == 0) w[wv] = s;
    __syncthreads();
    if (threadIdx.x == 0) out[0] = (w[0] + w[1] + w[2] + w[3]) * inv;
}

extern "C" void kernel_launch(void* const* d_in, const int* in_sizes, int n_in,
                              void* d_out, int out_size, void* d_ws, size_t ws_size,
                              hipStream_t stream) {
    const float* pred = (const float*)d_in[0];   // [B,64] fp32
    const int*   gt   = (const int*)d_in[1];     // [B] int32
    float* out     = (float*)d_out;
    float* partial = (float*)d_ws;
    const int rows = in_sizes[1];                // BATCH = 262144

    const int blocks = (rows + RPB - 1) / RPB;   // 2048
    tree_loss_partial<<<blocks, THREADS, 0, stream>>>(pred, gt, partial, rows);
    tree_loss_final<<<1, 256, 0, stream>>>(partial, blocks, out, 1.0f / (float)rows);
}